// Round 2
// baseline (75.834 us; speedup 1.0000x reference)
//
#include <hip/hip_runtime.h>
#include <cmath>

#define BN 8192
#define DIM 128
#define MARGIN_F 0.3f
#define NSPLIT 16           // column splits (512 cols each) -> 1024 blocks = 4/CU
#define CPS 512
#define NT 4                // 128-col B tiles per panel
#define NPART (NSPLIT * 2)  // per-row partials: split x wc
#define FBLK 32
#define IMAX 0x7FFFFFFF
#define IMIN 0x80000000

typedef __attribute__((ext_vector_type(4))) int i32x4;

__device__ __forceinline__ int imin3(int a, int b, int c) { return min(a, min(b, c)); }
__device__ __forceinline__ int imax3(int a, int b, int c) { return max(a, max(b, c)); }

// ---------------- K1: fp32 row norms -> sqv + k-major i8 quantized copy ----------------
// EnQ layout: 16B chunk (kgrp g, col c) at byte offset (g*BN + c)*16, g = k/16,
// holding i8 q[k] = rint(127 * e[k]) for k in [16g, 16g+16). Unit-norm rows -> |q| <= 127.
__global__ __launch_bounds__(256) void norm_cvt_k(
    const float* __restrict__ emb, float* __restrict__ sqv, unsigned short* __restrict__ EnQ16)
{
  int w = (blockIdx.x * blockDim.x + threadIdx.x) >> 6;  // one wave per row
  int lane = threadIdx.x & 63;
  if (w >= BN) return;
  float2 v = *reinterpret_cast<const float2*>(&emb[w * DIM + lane * 2]);
  float s = v.x * v.x + v.y * v.y;
  #pragma unroll
  for (int off = 32; off > 0; off >>= 1) s += __shfl_xor(s, off);
  float iv = 1.0f / fmaxf(sqrtf(s), 1e-12f);
  if (lane == 0) sqv[w] = s * iv * iv;
  int q0 = (int)rintf(127.0f * v.x * iv);
  int q1 = (int)rintf(127.0f * v.y * iv);
  unsigned short us = (unsigned short)((q0 & 255) | ((q1 & 255) << 8));
  int g = lane >> 3;                                  // k = 2*lane -> chunk g = lane/8
  EnQ16[(g * BN + w) * 8 + (lane & 7)] = us;
}

// ---------------- K2: fused i8-MFMA gram + hard mining (integer dot) ----------------
// ap = min idot over same-label (excl self), sentinel INT_MAX
// an = max idot over diff-label,             sentinel INT_MIN
// grid (64, 16), 256 threads = 4 waves (2x2 of 64x64 wave tiles).
// 1024 blocks = 4 blocks/CU (16 waves/CU) for latency hiding; r1 was 2/CU and
// measured latency-bound (Occupancy 15%, MfmaUtil 6%, VALUBusy 21%).
// B tiles 128 cols x 128 k x 1B = 16 KB, double-buffered (32 KB) via global_load_lds.
__global__ __launch_bounds__(256, 4) void gram_mine_mfma_k(
    const char* __restrict__ EnQ, const int* __restrict__ lab,
    int* __restrict__ ap_part, int* __restrict__ an_part)
{
  __shared__ __align__(16) char Bs[2][16384];   // 2 x 16 KB

  const int tid = threadIdx.x;
  const int w = tid >> 6, l = tid & 63;
  const int wr = w >> 1, wc = w & 1;
  const int lrow = l & 15, lkg = l >> 4;

  const int rowBase = blockIdx.x * 128 + wr * 64;   // this wave's 64 rows
  const int panel   = blockIdx.y * CPS;

  // A fragments: 4 row-tiles x 2 K-steps (K=64 each), 16B per frag, coalesced
  i32x4 a[4][2];
  #pragma unroll
  for (int mi = 0; mi < 4; ++mi)
    #pragma unroll
    for (int kk = 0; kk < 2; ++kk)
      a[mi][kk] = *reinterpret_cast<const i32x4*>(
          EnQ + (((size_t)((kk << 2) + lkg) * BN + rowBase + mi * 16 + lrow) << 4));

  // byte-packed labels for the 16 rows this lane owns (labels < 128)
  unsigned rlbp[4];
  #pragma unroll
  for (int mi = 0; mi < 4; ++mi) {
    int rb = rowBase + mi * 16 + lkg * 4;
    rlbp[mi] = (unsigned)(lab[rb] & 255) | ((unsigned)(lab[rb + 1] & 255) << 8) |
               ((unsigned)(lab[rb + 2] & 255) << 16) | ((unsigned)(lab[rb + 3] & 255) << 24);
  }

  int ap[4][4], an[4][4];
  #pragma unroll
  for (int mi = 0; mi < 4; ++mi)
    #pragma unroll
    for (int r = 0; r < 4; ++r) { ap[mi][r] = IMAX; an[mi][r] = IMIN; }

  // async stage of one 128-col tile (1024 slots x 16B): wave w covers [w*256, w*256+256)
  auto stage = [&](int buf, int colTile) {
    #pragma unroll
    for (int i = 0; i < 4; ++i) {
      int s0 = (w << 8) + (i << 6);          // wave-uniform slot base
      int s  = s0 + l;
      const char* gp = EnQ + (((size_t)(s >> 7) * BN + colTile + (s & 127)) << 4);
      __builtin_amdgcn_global_load_lds(
          (const __attribute__((address_space(1))) void*)gp,
          (__attribute__((address_space(3))) void*)(&Bs[buf][s0 * 16]),
          16, 0, 0);
    }
  };

  stage(0, panel);
  __syncthreads();   // drains vmcnt(0) then barrier

  int cur = 0;
  #pragma unroll 1
  for (int ct = 0; ct < NT; ++ct) {
    const int colTile = panel + ct * 128;
    const int colBase = colTile + wc * 64;

    if (ct + 1 < NT) stage(cur ^ 1, colTile + 128);   // in flight during compute

    // column labels for this wave's 64 cols
    int clb[4];
    #pragma unroll
    for (int ni = 0; ni < 4; ++ni) clb[ni] = lab[colBase + ni * 16 + lrow];

    const bool diag = (rowBase == colBase);

    #pragma unroll
    for (int half = 0; half < 2; ++half) {
      const int n0 = half * 2, n1 = half * 2 + 1;

      i32x4 acc[4][2] = {};
      #pragma unroll
      for (int kk = 0; kk < 2; ++kk) {
        i32x4 b[2];
        #pragma unroll
        for (int n = 0; n < 2; ++n)
          b[n] = *reinterpret_cast<const i32x4*>(
              &Bs[cur][(((kk << 2) + lkg) * 128 + wc * 64 + (n0 + n) * 16 + lrow) * 16]);
        #pragma unroll
        for (int mi = 0; mi < 4; ++mi)
          #pragma unroll
          for (int n = 0; n < 2; ++n)
            acc[mi][n] = __builtin_amdgcn_mfma_i32_16x16x64_i8(
                a[mi][kk], b[n], acc[mi][n], 0, 0, 0);
      }

      // epilogue: mine integer dot; pairs feed v_min3_i32/v_max3_i32
      if (diag) {
        #pragma unroll
        for (int mi = 0; mi < 4; ++mi)
          #pragma unroll
          for (int r = 0; r < 4; ++r) {
            int rl = (int)((rlbp[mi] >> (r * 8)) & 255u);
            int rloc = mi * 16 + lkg * 4 + r;
            int d0 = acc[mi][0][r], d1 = acc[mi][1][r];
            bool s0 = (rl == clb[n0]), s1 = (rl == clb[n1]);
            bool e0 = (rloc == n0 * 16 + lrow), e1 = (rloc == n1 * 16 + lrow);
            int p0 = (s0 && !e0) ? d0 : IMAX;
            int p1 = (s1 && !e1) ? d1 : IMAX;
            int q0 = s0 ? IMIN : d0;
            int q1 = s1 ? IMIN : d1;
            ap[mi][r] = imin3(ap[mi][r], p0, p1);
            an[mi][r] = imax3(an[mi][r], q0, q1);
          }
      } else {
        #pragma unroll
        for (int mi = 0; mi < 4; ++mi)
          #pragma unroll
          for (int r = 0; r < 4; ++r) {
            int rl = (int)((rlbp[mi] >> (r * 8)) & 255u);
            int d0 = acc[mi][0][r], d1 = acc[mi][1][r];
            bool s0 = (rl == clb[n0]), s1 = (rl == clb[n1]);
            int p0 = s0 ? d0 : IMAX;
            int p1 = s1 ? d1 : IMAX;
            int q0 = s0 ? IMIN : d0;
            int q1 = s1 ? IMIN : d1;
            ap[mi][r] = imin3(ap[mi][r], p0, p1);
            an[mi][r] = imax3(an[mi][r], q0, q1);
          }
      }
    }

    __syncthreads();   // drains staging vmcnt + publishes buf^1, protects reuse
    cur ^= 1;
  }

  // butterfly-reduce across the 16 lrow lanes sharing each C row, write partials
  const int part = blockIdx.y * 2 + wc;
  #pragma unroll
  for (int mi = 0; mi < 4; ++mi)
    #pragma unroll
    for (int r = 0; r < 4; ++r) {
      int p = ap[mi][r], n = an[mi][r];
      #pragma unroll
      for (int off = 1; off < 16; off <<= 1) {
        p = min(p, __shfl_xor(p, off));
        n = max(n, __shfl_xor(n, off));
      }
      if (lrow == 0) {
        int rg = rowBase + mi * 16 + lkg * 4 + r;
        ap_part[part * BN + rg] = p;
        an_part[part * BN + rg] = n;
      }
    }
}

// ---------------- K3a: per-row combine, d = sqrt(rs + 1 - 2*dot/127^2), margin ----------------
__global__ __launch_bounds__(256) void finalize_a_k(
    const int* __restrict__ ap_part, const int* __restrict__ an_part,
    const float* __restrict__ sqv,
    float* __restrict__ blk_sum, float* __restrict__ blk_cnt)
{
  int r = blockIdx.x * 256 + threadIdx.x;   // FBLK*256 == BN
  int apt = IMAX, ant = IMIN;               // min-idot pos / max-idot neg
  #pragma unroll 8
  for (int s = 0; s < NPART; ++s) {
    apt = min(apt, ap_part[s * BN + r]);
    ant = max(ant, an_part[s * BN + r]);
  }
  float sum = 0.f, cnt = 0.f;
  if (apt != IMAX && ant != IMIN) {
    const float sc = 2.0f / (127.0f * 127.0f);
    float rs1 = sqv[r] + 1.0f;
    float dap = sqrtf(fmaxf(fmaf(-sc, (float)apt, rs1), 0.f));
    float dan = sqrtf(fmaxf(fmaf(-sc, (float)ant, rs1), 0.f));
    sum = fmaxf(dap - dan + MARGIN_F, 0.f);
    cnt = 1.f;
  }
  #pragma unroll
  for (int off = 32; off > 0; off >>= 1) {
    sum += __shfl_xor(sum, off);
    cnt += __shfl_xor(cnt, off);
  }
  __shared__ float ssum[4], scnt[4];
  int wv = threadIdx.x >> 6;
  if ((threadIdx.x & 63) == 0) { ssum[wv] = sum; scnt[wv] = cnt; }
  __syncthreads();
  if (threadIdx.x == 0) {
    blk_sum[blockIdx.x] = ssum[0] + ssum[1] + ssum[2] + ssum[3];
    blk_cnt[blockIdx.x] = scnt[0] + scnt[1] + scnt[2] + scnt[3];
  }
}

// ---------------- K3b: final scalar ----------------
__global__ __launch_bounds__(64) void finalize_b_k(
    const float* __restrict__ blk_sum, const float* __restrict__ blk_cnt,
    float* __restrict__ out)
{
  int l = threadIdx.x;
  float s = (l < FBLK) ? blk_sum[l] : 0.f;
  float c = (l < FBLK) ? blk_cnt[l] : 0.f;
  #pragma unroll
  for (int off = 32; off > 0; off >>= 1) {
    s += __shfl_xor(s, off);
    c += __shfl_xor(c, off);
  }
  if (l == 0) out[0] = (c > 0.f) ? (s / c) : 0.f;
}

extern "C" void kernel_launch(void* const* d_in, const int* in_sizes, int n_in,
                              void* d_out, int out_size, void* d_ws, size_t ws_size,
                              hipStream_t stream)
{
  const float* emb = (const float*)d_in[0];
  const int*   lab = (const int*)d_in[1];
  float* out = (float*)d_out;
  float* ws  = (float*)d_ws;

  float* sqv     = ws;                          // BN floats
  int*   ap_part = (int*)(sqv + BN);            // NPART*BN ints
  int*   an_part = ap_part + NPART * BN;        // NPART*BN ints
  float* blk_sum = (float*)(an_part + NPART * BN);  // FBLK
  float* blk_cnt = blk_sum + FBLK;              // FBLK
  char*  EnQ     = (char*)(blk_cnt + FBLK);     // BN*DIM i8, k-major (~1 MB)

  norm_cvt_k<<<dim3(BN / 4), 256, 0, stream>>>(emb, sqv, (unsigned short*)EnQ);
  gram_mine_mfma_k<<<dim3(BN / 128, NSPLIT), 256, 0, stream>>>(EnQ, lab, ap_part, an_part);
  finalize_a_k<<<dim3(FBLK), 256, 0, stream>>>(ap_part, an_part, sqv, blk_sum, blk_cnt);
  finalize_b_k<<<dim3(1), 64, 0, stream>>>(blk_sum, blk_cnt, out);
}

// Round 3
// 37.774 us; speedup vs baseline: 2.0076x; 2.0076x over previous
//
#include <hip/hip_runtime.h>
#include <cmath>

#define BN 8192
#define DIM 128
#define MARGIN_F 0.3f
#define NSPLIT 16           // column splits (512 cols each) -> 1024 blocks = 4/CU available
#define CPS 512
#define NT 4                // 128-col B tiles per panel
#define NPART (NSPLIT * 2)  // per-row partials: split x wc
#define FBLK 32
#define IMAX 0x7FFFFFFF
#define IMIN 0x80000000

typedef __attribute__((ext_vector_type(4))) int i32x4;

__device__ __forceinline__ int imin3(int a, int b, int c) { return min(a, min(b, c)); }
__device__ __forceinline__ int imax3(int a, int b, int c) { return max(a, max(b, c)); }

// ---------------- K1: fp32 row norms -> sqv + k-major i8 quantized copy ----------------
// EnQ layout: 16B chunk (kgrp g, col c) at byte offset (g*BN + c)*16, g = k/16,
// holding i8 q[k] = rint(127 * e[k]) for k in [16g, 16g+16). Unit-norm rows -> |q| <= 127.
__global__ __launch_bounds__(256) void norm_cvt_k(
    const float* __restrict__ emb, float* __restrict__ sqv, unsigned short* __restrict__ EnQ16)
{
  int w = (blockIdx.x * blockDim.x + threadIdx.x) >> 6;  // one wave per row
  int lane = threadIdx.x & 63;
  if (w >= BN) return;
  float2 v = *reinterpret_cast<const float2*>(&emb[w * DIM + lane * 2]);
  float s = v.x * v.x + v.y * v.y;
  #pragma unroll
  for (int off = 32; off > 0; off >>= 1) s += __shfl_xor(s, off);
  float iv = 1.0f / fmaxf(sqrtf(s), 1e-12f);
  if (lane == 0) sqv[w] = s * iv * iv;
  int q0 = (int)rintf(127.0f * v.x * iv);
  int q1 = (int)rintf(127.0f * v.y * iv);
  unsigned short us = (unsigned short)((q0 & 255) | ((q1 & 255) << 8));
  int g = lane >> 3;                                  // k = 2*lane -> chunk g = lane/8
  EnQ16[(g * BN + w) * 8 + (lane & 7)] = us;
}

// ---------------- K2: fused i8-MFMA gram + hard mining (integer dot) ----------------
// ap = min idot over same-label (excl self), sentinel INT_MAX
// an = max idot over diff-label,             sentinel INT_MIN
// grid (64, 16), 256 threads = 4 waves (2x2 of 64x64 wave tiles).
// launch_bounds(256,2): r2's (256,4) capped unified VGPR+AGPR at 128 -> 64 arch
// VGPRs -> massive scratch spill (116 MB WRITE_SIZE, 68 us). (256,2) lets the
// natural ~88 VGPR allocation stand; 88+AGPRs fits the 128-granule so HW can
// still co-schedule 4 blocks/CU from the 1024-block grid.
// B tiles 128 cols x 128 k x 1B = 16 KB, double-buffered (32 KB) via global_load_lds.
__global__ __launch_bounds__(256, 2) void gram_mine_mfma_k(
    const char* __restrict__ EnQ, const int* __restrict__ lab,
    int* __restrict__ ap_part, int* __restrict__ an_part)
{
  __shared__ __align__(16) char Bs[2][16384];   // 2 x 16 KB

  const int tid = threadIdx.x;
  const int w = tid >> 6, l = tid & 63;
  const int wr = w >> 1, wc = w & 1;
  const int lrow = l & 15, lkg = l >> 4;

  const int rowBase = blockIdx.x * 128 + wr * 64;   // this wave's 64 rows
  const int panel   = blockIdx.y * CPS;

  // A fragments: 4 row-tiles x 2 K-steps (K=64 each), 16B per frag, coalesced
  i32x4 a[4][2];
  #pragma unroll
  for (int mi = 0; mi < 4; ++mi)
    #pragma unroll
    for (int kk = 0; kk < 2; ++kk)
      a[mi][kk] = *reinterpret_cast<const i32x4*>(
          EnQ + (((size_t)((kk << 2) + lkg) * BN + rowBase + mi * 16 + lrow) << 4));

  // byte-packed labels for the 16 rows this lane owns (labels < 128)
  unsigned rlbp[4];
  #pragma unroll
  for (int mi = 0; mi < 4; ++mi) {
    int rb = rowBase + mi * 16 + lkg * 4;
    rlbp[mi] = (unsigned)(lab[rb] & 255) | ((unsigned)(lab[rb + 1] & 255) << 8) |
               ((unsigned)(lab[rb + 2] & 255) << 16) | ((unsigned)(lab[rb + 3] & 255) << 24);
  }

  int ap[4][4], an[4][4];
  #pragma unroll
  for (int mi = 0; mi < 4; ++mi)
    #pragma unroll
    for (int r = 0; r < 4; ++r) { ap[mi][r] = IMAX; an[mi][r] = IMIN; }

  // async stage of one 128-col tile (1024 slots x 16B): wave w covers [w*256, w*256+256)
  auto stage = [&](int buf, int colTile) {
    #pragma unroll
    for (int i = 0; i < 4; ++i) {
      int s0 = (w << 8) + (i << 6);          // wave-uniform slot base
      int s  = s0 + l;
      const char* gp = EnQ + (((size_t)(s >> 7) * BN + colTile + (s & 127)) << 4);
      __builtin_amdgcn_global_load_lds(
          (const __attribute__((address_space(1))) void*)gp,
          (__attribute__((address_space(3))) void*)(&Bs[buf][s0 * 16]),
          16, 0, 0);
    }
  };

  stage(0, panel);
  __syncthreads();   // drains vmcnt(0) then barrier

  int cur = 0;
  #pragma unroll 1
  for (int ct = 0; ct < NT; ++ct) {
    const int colTile = panel + ct * 128;
    const int colBase = colTile + wc * 64;

    if (ct + 1 < NT) stage(cur ^ 1, colTile + 128);   // in flight during compute

    // column labels for this wave's 64 cols
    int clb[4];
    #pragma unroll
    for (int ni = 0; ni < 4; ++ni) clb[ni] = lab[colBase + ni * 16 + lrow];

    const bool diag = (rowBase == colBase);

    #pragma unroll
    for (int half = 0; half < 2; ++half) {
      const int n0 = half * 2, n1 = half * 2 + 1;

      i32x4 acc[4][2] = {};
      #pragma unroll
      for (int kk = 0; kk < 2; ++kk) {
        i32x4 b[2];
        #pragma unroll
        for (int n = 0; n < 2; ++n)
          b[n] = *reinterpret_cast<const i32x4*>(
              &Bs[cur][(((kk << 2) + lkg) * 128 + wc * 64 + (n0 + n) * 16 + lrow) * 16]);
        #pragma unroll
        for (int mi = 0; mi < 4; ++mi)
          #pragma unroll
          for (int n = 0; n < 2; ++n)
            acc[mi][n] = __builtin_amdgcn_mfma_i32_16x16x64_i8(
                a[mi][kk], b[n], acc[mi][n], 0, 0, 0);
      }

      // epilogue: mine integer dot; pairs feed v_min3_i32/v_max3_i32
      if (diag) {
        #pragma unroll
        for (int mi = 0; mi < 4; ++mi)
          #pragma unroll
          for (int r = 0; r < 4; ++r) {
            int rl = (int)((rlbp[mi] >> (r * 8)) & 255u);
            int rloc = mi * 16 + lkg * 4 + r;
            int d0 = acc[mi][0][r], d1 = acc[mi][1][r];
            bool s0 = (rl == clb[n0]), s1 = (rl == clb[n1]);
            bool e0 = (rloc == n0 * 16 + lrow), e1 = (rloc == n1 * 16 + lrow);
            int p0 = (s0 && !e0) ? d0 : IMAX;
            int p1 = (s1 && !e1) ? d1 : IMAX;
            int q0 = s0 ? IMIN : d0;
            int q1 = s1 ? IMIN : d1;
            ap[mi][r] = imin3(ap[mi][r], p0, p1);
            an[mi][r] = imax3(an[mi][r], q0, q1);
          }
      } else {
        #pragma unroll
        for (int mi = 0; mi < 4; ++mi)
          #pragma unroll
          for (int r = 0; r < 4; ++r) {
            int rl = (int)((rlbp[mi] >> (r * 8)) & 255u);
            int d0 = acc[mi][0][r], d1 = acc[mi][1][r];
            bool s0 = (rl == clb[n0]), s1 = (rl == clb[n1]);
            int p0 = s0 ? d0 : IMAX;
            int p1 = s1 ? d1 : IMAX;
            int q0 = s0 ? IMIN : d0;
            int q1 = s1 ? IMIN : d1;
            ap[mi][r] = imin3(ap[mi][r], p0, p1);
            an[mi][r] = imax3(an[mi][r], q0, q1);
          }
      }
    }

    __syncthreads();   // drains staging vmcnt + publishes buf^1, protects reuse
    cur ^= 1;
  }

  // butterfly-reduce across the 16 lrow lanes sharing each C row, write partials
  const int part = blockIdx.y * 2 + wc;
  #pragma unroll
  for (int mi = 0; mi < 4; ++mi)
    #pragma unroll
    for (int r = 0; r < 4; ++r) {
      int p = ap[mi][r], n = an[mi][r];
      #pragma unroll
      for (int off = 1; off < 16; off <<= 1) {
        p = min(p, __shfl_xor(p, off));
        n = max(n, __shfl_xor(n, off));
      }
      if (lrow == 0) {
        int rg = rowBase + mi * 16 + lkg * 4 + r;
        ap_part[part * BN + rg] = p;
        an_part[part * BN + rg] = n;
      }
    }
}

// ---------------- K3a: per-row combine, d = sqrt(rs + 1 - 2*dot/127^2), margin ----------------
__global__ __launch_bounds__(256) void finalize_a_k(
    const int* __restrict__ ap_part, const int* __restrict__ an_part,
    const float* __restrict__ sqv,
    float* __restrict__ blk_sum, float* __restrict__ blk_cnt)
{
  int r = blockIdx.x * 256 + threadIdx.x;   // FBLK*256 == BN
  int apt = IMAX, ant = IMIN;               // min-idot pos / max-idot neg
  #pragma unroll 8
  for (int s = 0; s < NPART; ++s) {
    apt = min(apt, ap_part[s * BN + r]);
    ant = max(ant, an_part[s * BN + r]);
  }
  float sum = 0.f, cnt = 0.f;
  if (apt != IMAX && ant != IMIN) {
    const float sc = 2.0f / (127.0f * 127.0f);
    float rs1 = sqv[r] + 1.0f;
    float dap = sqrtf(fmaxf(fmaf(-sc, (float)apt, rs1), 0.f));
    float dan = sqrtf(fmaxf(fmaf(-sc, (float)ant, rs1), 0.f));
    sum = fmaxf(dap - dan + MARGIN_F, 0.f);
    cnt = 1.f;
  }
  #pragma unroll
  for (int off = 32; off > 0; off >>= 1) {
    sum += __shfl_xor(sum, off);
    cnt += __shfl_xor(cnt, off);
  }
  __shared__ float ssum[4], scnt[4];
  int wv = threadIdx.x >> 6;
  if ((threadIdx.x & 63) == 0) { ssum[wv] = sum; scnt[wv] = cnt; }
  __syncthreads();
  if (threadIdx.x == 0) {
    blk_sum[blockIdx.x] = ssum[0] + ssum[1] + ssum[2] + ssum[3];
    blk_cnt[blockIdx.x] = scnt[0] + scnt[1] + scnt[2] + scnt[3];
  }
}

// ---------------- K3b: final scalar ----------------
__global__ __launch_bounds__(64) void finalize_b_k(
    const float* __restrict__ blk_sum, const float* __restrict__ blk_cnt,
    float* __restrict__ out)
{
  int l = threadIdx.x;
  float s = (l < FBLK) ? blk_sum[l] : 0.f;
  float c = (l < FBLK) ? blk_cnt[l] : 0.f;
  #pragma unroll
  for (int off = 32; off > 0; off >>= 1) {
    s += __shfl_xor(s, off);
    c += __shfl_xor(c, off);
  }
  if (l == 0) out[0] = (c > 0.f) ? (s / c) : 0.f;
}

extern "C" void kernel_launch(void* const* d_in, const int* in_sizes, int n_in,
                              void* d_out, int out_size, void* d_ws, size_t ws_size,
                              hipStream_t stream)
{
  const float* emb = (const float*)d_in[0];
  const int*   lab = (const int*)d_in[1];
  float* out = (float*)d_out;
  float* ws  = (float*)d_ws;

  float* sqv     = ws;                          // BN floats
  int*   ap_part = (int*)(sqv + BN);            // NPART*BN ints
  int*   an_part = ap_part + NPART * BN;        // NPART*BN ints
  float* blk_sum = (float*)(an_part + NPART * BN);  // FBLK
  float* blk_cnt = blk_sum + FBLK;              // FBLK
  char*  EnQ     = (char*)(blk_cnt + FBLK);     // BN*DIM i8, k-major (~1 MB)

  norm_cvt_k<<<dim3(BN / 4), 256, 0, stream>>>(emb, sqv, (unsigned short*)EnQ);
  gram_mine_mfma_k<<<dim3(BN / 128, NSPLIT), 256, 0, stream>>>(EnQ, lab, ap_part, an_part);
  finalize_a_k<<<dim3(FBLK), 256, 0, stream>>>(ap_part, an_part, sqv, blk_sum, blk_cnt);
  finalize_b_k<<<dim3(1), 64, 0, stream>>>(blk_sum, blk_cnt, out);
}

// Round 4
// 35.816 us; speedup vs baseline: 2.1173x; 1.0547x over previous
//
#include <hip/hip_runtime.h>
#include <cmath>

#define BN 8192
#define DIM 128
#define MARGIN_F 0.3f
#define NSPLIT 8            // column splits (1024 cols each) — r0's proven config
#define CPS 1024
#define NT 8                // 128-col B tiles per panel
#define IMAX 0x7FFFFFFF
#define IMIN 0x80000000

typedef __attribute__((ext_vector_type(4))) int i32x4;

__device__ __forceinline__ int imin3(int a, int b, int c) { return min(a, min(b, c)); }
__device__ __forceinline__ int imax3(int a, int b, int c) { return max(a, max(b, c)); }

// ---------------- K1: fp32 row norms -> sqv + k-major i8 quantized copy ----------------
// EnQ layout: 16B chunk (kgrp g, col c) at byte offset (g*BN + c)*16, g = k/16,
// holding i8 q[k] = rint(127 * e[k]) for k in [16g, 16g+16). Unit-norm rows -> |q| <= 127.
// Also seeds ap_f/an_f sentinels for K2's atomic min/max (visible via end-of-kernel release).
__global__ __launch_bounds__(256) void norm_cvt_k(
    const float* __restrict__ emb, float* __restrict__ sqv, unsigned short* __restrict__ EnQ16,
    int* __restrict__ ap_f, int* __restrict__ an_f)
{
  int gt = blockIdx.x * blockDim.x + threadIdx.x;
  if (gt < BN) { ap_f[gt] = IMAX; an_f[gt] = IMIN; }

  int w = gt >> 6;  // one wave per row
  int lane = threadIdx.x & 63;
  if (w >= BN) return;
  float2 v = *reinterpret_cast<const float2*>(&emb[w * DIM + lane * 2]);
  float s = v.x * v.x + v.y * v.y;
  #pragma unroll
  for (int off = 32; off > 0; off >>= 1) s += __shfl_xor(s, off);
  float iv = 1.0f / fmaxf(sqrtf(s), 1e-12f);
  if (lane == 0) sqv[w] = s * iv * iv;
  int q0 = (int)rintf(127.0f * v.x * iv);
  int q1 = (int)rintf(127.0f * v.y * iv);
  unsigned short us = (unsigned short)((q0 & 255) | ((q1 & 255) << 8));
  int g = lane >> 3;                                  // k = 2*lane -> chunk g = lane/8
  EnQ16[(g * BN + w) * 8 + (lane & 7)] = us;
}

// ---------------- K2: fused i8-MFMA gram + hard mining (integer dot) ----------------
// ap_f[r] = min idot over same-label (excl self), an_f[r] = max idot over diff-label,
// merged across blocks via device-scope atomicMin/atomicMax (coherent across XCDs,
// order-free, exact for ints; no fences needed — unlike r1's threadfence disaster).
// grid (64, 8), 256 threads = 4 waves (2x2 of 64x64 wave tiles), r0 structure.
// B tiles 128 cols x 128 k x 1B = 16 KB, double-buffered (32 KB) via global_load_lds.
__global__ __launch_bounds__(256, 2) void gram_mine_mfma_k(
    const char* __restrict__ EnQ, const int* __restrict__ lab,
    int* __restrict__ ap_f, int* __restrict__ an_f)
{
  __shared__ __align__(16) char Bs[2][16384];   // 2 x 16 KB

  const int tid = threadIdx.x;
  const int w = tid >> 6, l = tid & 63;
  const int wr = w >> 1, wc = w & 1;
  const int lrow = l & 15, lkg = l >> 4;

  const int rowBase = blockIdx.x * 128 + wr * 64;   // this wave's 64 rows
  const int panel   = blockIdx.y * CPS;

  // A fragments: 4 row-tiles x 2 K-steps (K=64 each), 16B per frag, coalesced
  i32x4 a[4][2];
  #pragma unroll
  for (int mi = 0; mi < 4; ++mi)
    #pragma unroll
    for (int kk = 0; kk < 2; ++kk)
      a[mi][kk] = *reinterpret_cast<const i32x4*>(
          EnQ + (((size_t)((kk << 2) + lkg) * BN + rowBase + mi * 16 + lrow) << 4));

  // byte-packed labels for the 16 rows this lane owns (labels < 128)
  unsigned rlbp[4];
  #pragma unroll
  for (int mi = 0; mi < 4; ++mi) {
    int rb = rowBase + mi * 16 + lkg * 4;
    rlbp[mi] = (unsigned)(lab[rb] & 255) | ((unsigned)(lab[rb + 1] & 255) << 8) |
               ((unsigned)(lab[rb + 2] & 255) << 16) | ((unsigned)(lab[rb + 3] & 255) << 24);
  }

  int ap[4][4], an[4][4];
  #pragma unroll
  for (int mi = 0; mi < 4; ++mi)
    #pragma unroll
    for (int r = 0; r < 4; ++r) { ap[mi][r] = IMAX; an[mi][r] = IMIN; }

  const i32x4 zf = {0, 0, 0, 0};   // shared zero C-operand: no per-half acc zero-init movs

  // async stage of one 128-col tile (1024 slots x 16B): wave w covers [w*256, w*256+256)
  auto stage = [&](int buf, int colTile) {
    #pragma unroll
    for (int i = 0; i < 4; ++i) {
      int s0 = (w << 8) + (i << 6);          // wave-uniform slot base
      int s  = s0 + l;
      const char* gp = EnQ + (((size_t)(s >> 7) * BN + colTile + (s & 127)) << 4);
      __builtin_amdgcn_global_load_lds(
          (const __attribute__((address_space(1))) void*)gp,
          (__attribute__((address_space(3))) void*)(&Bs[buf][s0 * 16]),
          16, 0, 0);
    }
  };

  stage(0, panel);
  __syncthreads();   // drains vmcnt(0) then barrier

  int cur = 0;
  #pragma unroll 1
  for (int ct = 0; ct < NT; ++ct) {
    const int colTile = panel + ct * 128;
    const int colBase = colTile + wc * 64;

    if (ct + 1 < NT) stage(cur ^ 1, colTile + 128);   // in flight during compute

    // column labels for this wave's 64 cols
    int clb[4];
    #pragma unroll
    for (int ni = 0; ni < 4; ++ni) clb[ni] = lab[colBase + ni * 16 + lrow];

    const bool diag = (rowBase == colBase);

    #pragma unroll
    for (int half = 0; half < 2; ++half) {
      const int n0 = half * 2, n1 = half * 2 + 1;

      i32x4 acc[4][2];
      {  // kk = 0: C = zf (no zero-init of acc needed)
        i32x4 b[2];
        #pragma unroll
        for (int n = 0; n < 2; ++n)
          b[n] = *reinterpret_cast<const i32x4*>(
              &Bs[cur][((0 + lkg) * 128 + wc * 64 + (n0 + n) * 16 + lrow) * 16]);
        #pragma unroll
        for (int mi = 0; mi < 4; ++mi)
          #pragma unroll
          for (int n = 0; n < 2; ++n)
            acc[mi][n] = __builtin_amdgcn_mfma_i32_16x16x64_i8(
                a[mi][0], b[n], zf, 0, 0, 0);
      }
      {  // kk = 1: chain
        i32x4 b[2];
        #pragma unroll
        for (int n = 0; n < 2; ++n)
          b[n] = *reinterpret_cast<const i32x4*>(
              &Bs[cur][((4 + lkg) * 128 + wc * 64 + (n0 + n) * 16 + lrow) * 16]);
        #pragma unroll
        for (int mi = 0; mi < 4; ++mi)
          #pragma unroll
          for (int n = 0; n < 2; ++n)
            acc[mi][n] = __builtin_amdgcn_mfma_i32_16x16x64_i8(
                a[mi][1], b[n], acc[mi][n], 0, 0, 0);
      }

      // epilogue: mine integer dot; pairs feed v_min3_i32/v_max3_i32
      if (diag) {
        #pragma unroll
        for (int mi = 0; mi < 4; ++mi)
          #pragma unroll
          for (int r = 0; r < 4; ++r) {
            int rl = (int)((rlbp[mi] >> (r * 8)) & 255u);
            int rloc = mi * 16 + lkg * 4 + r;
            int d0 = acc[mi][0][r], d1 = acc[mi][1][r];
            bool s0 = (rl == clb[n0]), s1 = (rl == clb[n1]);
            bool e0 = (rloc == n0 * 16 + lrow), e1 = (rloc == n1 * 16 + lrow);
            int p0 = (s0 && !e0) ? d0 : IMAX;
            int p1 = (s1 && !e1) ? d1 : IMAX;
            int q0 = s0 ? IMIN : d0;
            int q1 = s1 ? IMIN : d1;
            ap[mi][r] = imin3(ap[mi][r], p0, p1);
            an[mi][r] = imax3(an[mi][r], q0, q1);
          }
      } else {
        #pragma unroll
        for (int mi = 0; mi < 4; ++mi)
          #pragma unroll
          for (int r = 0; r < 4; ++r) {
            int rl = (int)((rlbp[mi] >> (r * 8)) & 255u);
            int d0 = acc[mi][0][r], d1 = acc[mi][1][r];
            bool s0 = (rl == clb[n0]), s1 = (rl == clb[n1]);
            int p0 = s0 ? d0 : IMAX;
            int p1 = s1 ? d1 : IMAX;
            int q0 = s0 ? IMIN : d0;
            int q1 = s1 ? IMIN : d1;
            ap[mi][r] = imin3(ap[mi][r], p0, p1);
            an[mi][r] = imax3(an[mi][r], q0, q1);
          }
      }
    }

    __syncthreads();   // drains staging vmcnt + publishes buf^1, protects reuse
    cur ^= 1;
  }

  // butterfly-reduce across the 16 lrow lanes sharing each C row, then one
  // device-scope atomic per row (fire-and-forget, no return -> no sc0 path)
  #pragma unroll
  for (int mi = 0; mi < 4; ++mi)
    #pragma unroll
    for (int r = 0; r < 4; ++r) {
      int p = ap[mi][r], n = an[mi][r];
      #pragma unroll
      for (int off = 1; off < 16; off <<= 1) {
        p = min(p, __shfl_xor(p, off));
        n = max(n, __shfl_xor(n, off));
      }
      if (lrow == 0) {
        int rg = rowBase + mi * 16 + lkg * 4 + r;
        atomicMin(&ap_f[rg], p);
        atomicMax(&an_f[rg], n);
      }
    }
}

// ---------------- K3: single-block finalize (plain loads — dispatch acquire makes
// K2's atomic results visible), deterministic reduction tree ----------------
__global__ __launch_bounds__(1024) void finalize_k(
    const int* __restrict__ ap_f, const int* __restrict__ an_f,
    const float* __restrict__ sqv, float* __restrict__ out)
{
  int t = threadIdx.x;
  float sum = 0.f, cnt = 0.f;
  #pragma unroll
  for (int i = 0; i < BN / 1024; ++i) {
    int r = i * 1024 + t;
    int apt = ap_f[r], ant = an_f[r];
    if (apt != IMAX && ant != IMIN) {
      const float sc = 2.0f / (127.0f * 127.0f);
      float rs1 = sqv[r] + 1.0f;
      float dap = sqrtf(fmaxf(fmaf(-sc, (float)apt, rs1), 0.f));
      float dan = sqrtf(fmaxf(fmaf(-sc, (float)ant, rs1), 0.f));
      sum += fmaxf(dap - dan + MARGIN_F, 0.f);
      cnt += 1.f;
    }
  }
  #pragma unroll
  for (int off = 32; off > 0; off >>= 1) {
    sum += __shfl_xor(sum, off);
    cnt += __shfl_xor(cnt, off);
  }
  __shared__ float ssum[16], scnt[16];
  int wv = t >> 6;
  if ((t & 63) == 0) { ssum[wv] = sum; scnt[wv] = cnt; }
  __syncthreads();
  if (t == 0) {
    float s = 0.f, c = 0.f;
    #pragma unroll
    for (int i = 0; i < 16; ++i) { s += ssum[i]; c += scnt[i]; }
    out[0] = (c > 0.f) ? (s / c) : 0.f;
  }
}

extern "C" void kernel_launch(void* const* d_in, const int* in_sizes, int n_in,
                              void* d_out, int out_size, void* d_ws, size_t ws_size,
                              hipStream_t stream)
{
  const float* emb = (const float*)d_in[0];
  const int*   lab = (const int*)d_in[1];
  float* out = (float*)d_out;
  float* ws  = (float*)d_ws;

  float* sqv  = ws;                       // BN floats
  int*   ap_f = (int*)(sqv + BN);         // BN ints
  int*   an_f = ap_f + BN;                // BN ints
  char*  EnQ  = (char*)(an_f + BN);       // BN*DIM i8, k-major (~1 MB)

  norm_cvt_k<<<dim3(BN / 4), 256, 0, stream>>>(emb, sqv, (unsigned short*)EnQ, ap_f, an_f);
  gram_mine_mfma_k<<<dim3(BN / 128, NSPLIT), 256, 0, stream>>>(EnQ, lab, ap_f, an_f);
  finalize_k<<<dim3(1), 1024, 0, stream>>>(ap_f, an_f, sqv, out);
}